// Round 23
// baseline (363.403 us; speedup 1.0000x reference)
//
#include <hip/hip_runtime.h>
#include <math.h>

// Problem constants (fixed by the reference module)
#define NB 8
#define LTOK 4096
#define CH 384
#define DH 192
#define HH 64
#define WW 64
#define NCHK 128     // chunks per sequence
#define CHS 32       // steps per chunk (LTOK / NCHK)

static constexpr long BLC  = (long)NB * LTOK * CH;   // 12,582,912 elements
static constexpr long CST  = (long)32 * NCHK * DH;   // 786,432 per chunk-state buffer

typedef unsigned short u16;
typedef u16   u16x8 __attribute__((ext_vector_type(8)));
typedef short s16x8 __attribute__((ext_vector_type(8)));
typedef float f32x4 __attribute__((ext_vector_type(4)));

__device__ inline u16 f2bf(float f){
  unsigned int u = __float_as_uint(f);
  return (u16)((u + 0x7FFFu + ((u >> 16) & 1u)) >> 16);
}
__device__ inline float bf2f(u16 h){ return __uint_as_float(((unsigned int)h) << 16); }
__device__ inline float fsigmoid(float x){ return 1.f / (1.f + __expf(-x)); }
// pack two f32 -> two bf16 in one u32: lo = src0, hi = src1
__device__ inline unsigned cvt_pk_bf16(float lo, float hi){
  unsigned r;
  asm("v_cvt_pk_bf16_f32 %0, %1, %2" : "=v"(r) : "v"(lo), "v"(hi));
  return r;
}
// async global->LDS, 16 B per lane; l must be wave-uniform (HW: base + lane*16)
__device__ inline void gl16(const u16* g, u16* l){
  __builtin_amdgcn_global_load_lds(
      (const __attribute__((address_space(1))) void*)g,
      (__attribute__((address_space(3))) void*)l, 16, 0, 0);
}

// LDS scan-buffer column swizzle: spreads kg-lanes across banks (2-way max)
#define SCOL(ml, c) ((c) ^ ((((ml) >> 2) & 3) << 4))

template<int NW>
__device__ inline float blockSum(float v, float* sm){
  #pragma unroll
  for (int o = 32; o > 0; o >>= 1) v += __shfl_down(v, o);
  int lane = threadIdx.x & 63, wv = threadIdx.x >> 6;
  if (lane == 0) sm[wv] = v;
  __syncthreads();
  if (threadIdx.x == 0){ float t = 0.f; for (int i = 0; i < NW; i++) t += sm[i]; sm[0] = t; }
  __syncthreads();
  float t = sm[0];
  __syncthreads();
  return t;
}

// ---------------- LayerNorm stats per token (no xn materialization) ----------------
__global__ __launch_bounds__(128) void k_lnstat(const float* __restrict__ x,
    float* __restrict__ mst){
  __shared__ float sm[2];
  long row = blockIdx.x;
  int t = threadIdx.x;
  const float* xr = x + row * CH;
  float v0 = xr[t], v1 = xr[t + 128], v2 = xr[t + 256];
  float s = blockSum<2>(v0 + v1 + v2, sm);
  float m = s * (1.f / CH);
  float d0 = v0 - m, d1 = v1 - m, d2 = v2 - m;
  float vs = blockSum<2>(d0*d0 + d1*d1 + d2*d2, sm);
  float inv = rsqrtf(vs * (1.f / CH) + 1e-5f);
  if (t == 0){ mst[row * 2] = m; mst[row * 2 + 1] = inv; }
}

// ---------------- partial pooling (LN applied inline from stats) ----------------
__global__ __launch_bounds__(128) void k_pool(const float* __restrict__ x,
    const float* __restrict__ mst, const float* __restrict__ g,
    const float* __restrict__ b, float* __restrict__ pp){
  __shared__ float smst[512];
  int c = blockIdx.x * 128 + threadIdx.x;
  int chunk = blockIdx.y, bb = blockIdx.z;
  long t0 = (long)bb * LTOK + chunk * 256;
  for (int i = threadIdx.x; i < 512; i += 128) smst[i] = mst[t0 * 2 + i];
  __syncthreads();
  float gc = g[c], bc_ = b[c];
  float s = 0.f;
  for (int n = 0; n < 256; n++){
    float m = smst[n * 2], inv = smst[n * 2 + 1];
    s += (x[(t0 + n) * CH + c] - m) * inv * gc + bc_;
  }
  pp[((long)bb * 16 + chunk) * CH + c] = s;
}

// ---------------- score MLP + stable argsort (descending) ----------------
__global__ __launch_bounds__(384) void k_score(const float* __restrict__ pp,
    const float* __restrict__ w1, const float* __restrict__ b1,
    const float* __restrict__ w2, const float* __restrict__ b2,
    int* __restrict__ sidx, int* __restrict__ inv){
  __shared__ float poolv[CH];
  __shared__ float hid[192];
  __shared__ float sc[CH];
  int b = blockIdx.x, t = threadIdx.x;
  float s = 0.f;
  for (int ch = 0; ch < 16; ch++) s += pp[((long)b * 16 + ch) * CH + t];
  poolv[t] = s * (1.f / LTOK);
  __syncthreads();
  if (t < 192){
    float h = b1[t];
    for (int c = 0; c < CH; c++) h += poolv[c] * w1[t * CH + c];
    hid[t] = fmaxf(h, 0.f);
  }
  __syncthreads();
  {
    float h = b2[t];
    for (int j = 0; j < 192; j++) h += hid[j] * w2[t * 192 + j];
    sc[t] = 1.f / (1.f + expf(-h));
  }
  __syncthreads();
  float mys = sc[t];
  int rank = 0;
  for (int j = 0; j < CH; j++){
    float o = sc[j];
    rank += (o > mys) || (o == mys && j < t);
  }
  sidx[b * CH + rank] = t;
  inv[b * CH + t] = rank;
}

// ---------------- merged prep: weight casts + Atab + conv-w transpose + fused dt M ----------------
__global__ __launch_bounds__(256) void k_preps(const float* __restrict__ in_proj,
    const float* __restrict__ op_w, const float* __restrict__ proj_w,
    const float* __restrict__ alog, const float* __restrict__ cw,
    const float* __restrict__ dtw, const float* __restrict__ xpw,
    u16* __restrict__ wip, u16* __restrict__ wop, u16* __restrict__ wpj,
    float* __restrict__ Atab, u16* __restrict__ cwb, u16* __restrict__ Mw){
  const int N1 = 2*384*192;        // wip
  const int N2 = N1 + 2*192*192;   // wop
  const int N3 = N2 + 384*384;     // wpj
  const int N4 = N3 + 4*192;       // Atab
  const int N5 = N4 + 2*9*DH;      // cwb
  const int N6 = N5 + 4*36864;     // Mw
  int i = blockIdx.x * 256 + threadIdx.x;
  if (i < N1)      wip[i] = f2bf(in_proj[i]);
  else if (i < N2) wop[i-N1] = f2bf(op_w[i-N1]);
  else if (i < N3) wpj[i-N2] = f2bf(proj_w[i-N2]);
  else if (i < N4) Atab[i-N3] = -expf(alog[i-N3]);
  else if (i < N5){
    int r = i - N4;
    int g = r / (9*DH); int r2 = r - g*9*DH;
    int tap = r2 / DH, di = r2 - tap*DH;
    cwb[r] = f2bf(cw[((long)g*DH + di)*9 + tap]);
  } else if (i < N6){
    int r = i - N5;
    int gk = r / 36864; int idx = r - gk * 36864;
    int g = gk >> 1, k = gk & 1;
    int di = idx / 192, c = idx - di * 192;
    float s = 0.f;
    #pragma unroll
    for (int q = 0; q < 12; q++)
      s += dtw[((long)gk * 192 + di) * 12 + q] * xpw[(long)g * 5376 + (k * 14 + q) * 192 + c];
    Mw[(long)gk * 36864 + idx] = f2bf(s);
  }
}

// ---------------- gather sorted channels + LN inline + cast to bf16 ----------------
__global__ __launch_bounds__(384) void k_castgather(const float* __restrict__ x,
    const float* __restrict__ mst, const int* __restrict__ sidx,
    const float* __restrict__ g, const float* __restrict__ b,
    u16* __restrict__ As){
  long row = blockIdx.x;
  int bb = (int)(row >> 12);
  int t = threadIdx.x;
  int c = sidx[bb * CH + t];
  float m = mst[row * 2], inv = mst[row * 2 + 1];
  float v = (x[row * CH + c] - m) * inv * g[c] + b[c];
  As[row * CH + t] = f2bf(v);
}

// ---------------- prep gate-MLP weights: gathered w1 (per batch), padded w2, b1 ----------------
__global__ __launch_bounds__(256) void k_prepw(const float* __restrict__ w1,
    const float* __restrict__ b1, const float* __restrict__ w2,
    const int* __restrict__ sidx, u16* __restrict__ w1g, u16* __restrict__ w2p,
    float* __restrict__ b1p){
  int b = blockIdx.x, tid = threadIdx.x;
  if (b < NB){
    const int* sx = sidx + b * CH;
    for (int i = tid; i < 32 * CH; i += 256){
      int j = i / CH, r = i - j * CH;
      float v = (j < 24) ? w1[j * CH + sx[r]] : 0.f;
      w1g[(long)b * 32 * CH + i] = f2bf(v);
    }
  } else {
    for (int i = tid; i < CH * 32; i += 256){
      int n = i >> 5, j = i & 31;
      w2p[i] = f2bf((j < 24) ? w2[n * 24 + j] : 0.f);
    }
    if (tid < 32) b1p[tid] = (tid < 24) ? b1[tid] : 0.f;
  }
}

// ---------------- gate stage 1: hid = relu(As @ w1g^T + b1p), bf16 out ----------------
__global__ __launch_bounds__(256) void k_hid(const u16* __restrict__ As,
    const u16* __restrict__ w1g, const float* __restrict__ b1p,
    u16* __restrict__ hidp){
  __shared__ u16 sA[128 * 32];
  __shared__ u16 sB[32 * 32];
  int b = blockIdx.y;
  const u16* Ab = As + (long)b * LTOK * CH;
  const u16* Bb = w1g + (long)b * 32 * CH;
  int tid = threadIdx.x;
  int m0 = blockIdx.x * 128;
  int wv = tid >> 6, l = tid & 63;
  int wm = wv * 32;
  int kg = l >> 4, lr = l & 15;

  f32x4 acc[2][2];
  #pragma unroll
  for (int i = 0; i < 2; i++)
    #pragma unroll
    for (int j = 0; j < 2; j++)
      #pragma unroll
      for (int r = 0; r < 4; r++) acc[i][j][r] = 0.f;

  int aoffU[2], boffU[2];
  #pragma unroll
  for (int i = 0; i < 2; i++){
    int r = wm + i * 16 + lr;
    aoffU[i] = r * 32 + ((kg * 8) ^ ((r & 3) << 3));
  }
  #pragma unroll
  for (int j = 0; j < 2; j++){
    int r = j * 16 + lr;
    boffU[j] = r * 32 + ((kg * 8) ^ ((r & 3) << 3));
  }

  u16x8 ra[2], rbv;
  #pragma unroll
  for (int q = 0; q < 2; q++){
    int i = q * 256 + tid; int row = i >> 2, sl = i & 3, ss = sl ^ (row & 3);
    ra[q] = *(const u16x8*)(Ab + (long)(m0 + row) * CH + ss * 8);
  }
  if (tid < 128){
    int row = tid >> 2, sl = tid & 3, ss = sl ^ (row & 3);
    rbv = *(const u16x8*)(Bb + (long)row * CH + ss * 8);
  }

  const int nks = CH / 32;   // 12
  for (int ks = 0; ks < nks; ks++){
    __syncthreads();
    #pragma unroll
    for (int q = 0; q < 2; q++){
      int i = q * 256 + tid; int row = i >> 2, sl = i & 3;
      *(u16x8*)(sA + row * 32 + sl * 8) = ra[q];
    }
    if (tid < 128){
      int row = tid >> 2, sl = tid & 3;
      *(u16x8*)(sB + row * 32 + sl * 8) = rbv;
    }
    __syncthreads();
    if (ks + 1 < nks){
      int k0 = (ks + 1) * 32;
      #pragma unroll
      for (int q = 0; q < 2; q++){
        int i = q * 256 + tid; int row = i >> 2, sl = i & 3, ss = sl ^ (row & 3);
        ra[q] = *(const u16x8*)(Ab + (long)(m0 + row) * CH + k0 + ss * 8);
      }
      if (tid < 128){
        int row = tid >> 2, sl = tid & 3, ss = sl ^ (row & 3);
        rbv = *(const u16x8*)(Bb + (long)row * CH + k0 + ss * 8);
      }
    }
    s16x8 af[2], bfr[2];
    #pragma unroll
    for (int i = 0; i < 2; i++) af[i] = *(const s16x8*)(sA + aoffU[i]);
    #pragma unroll
    for (int j = 0; j < 2; j++) bfr[j] = *(const s16x8*)(sB + boffU[j]);
    #pragma unroll
    for (int i = 0; i < 2; i++)
      #pragma unroll
      for (int j = 0; j < 2; j++)
        acc[i][j] = __builtin_amdgcn_mfma_f32_16x16x32_bf16(af[i], bfr[j], acc[i][j], 0, 0, 0);
  }

  #pragma unroll
  for (int i = 0; i < 2; i++)
    #pragma unroll
    for (int j = 0; j < 2; j++)
      #pragma unroll
      for (int r = 0; r < 4; r++){
        int m = m0 + wm + i * 16 + kg * 4 + r;
        int n = j * 16 + lr;
        float v = fmaxf(acc[i][j][r] + b1p[n], 0.f);
        hidp[((long)b * LTOK + m) * 32 + n] = f2bf(v);
      }
}

// ---------------- full-K staged bf16 MFMA GEMM: C = A @ B^T ----------------
// BM=BN=64; K staged in NITER panels of 192 (one barrier per panel).
// MODE 1: n<192 -> ((u16*)Cf) bf16 [m*192+n]; n>=192 -> Ch bf16 silu(v)
// MODE 2: Ch bf16 [zc + m*ldc + n]
// MODE 3: Cf fp32 = resid + skip*(v + bias[n])
template<int NITER, int MODE>
__global__ __launch_bounds__(256) void k_mm2(
    const u16* __restrict__ A, int lda, long aOuter, long aInner,
    const u16* __restrict__ B, int ldb, long bInner,
    float* __restrict__ Cf, u16* __restrict__ Ch,
    long cOuter, long cInner, int ldc,
    int innerCnt,
    const float* __restrict__ bias, const float* __restrict__ resid,
    const float* __restrict__ skip){
  __shared__ u16 sA[64 * 192];
  __shared__ u16 sB[64 * 192];

  int bz = blockIdx.z;
  int bo = bz / innerCnt, bi_ = bz - bo * innerCnt;
  const u16* Ab = A + (long)bo * aOuter + (long)bi_ * aInner;
  const u16* Bb = B + (long)bi_ * bInner;
  int tid = threadIdx.x;
  int m0 = blockIdx.y * 64, n0 = blockIdx.x * 64;
  int wv = tid >> 6, l = tid & 63;
  int wm = (wv >> 1) * 32, wn = (wv & 1) * 32;
  int kg = l >> 4, lr = l & 15;
  int wb = tid & 192;                 // wave-uniform lane-block base (slot units)

  f32x4 acc[2][2];
  #pragma unroll
  for (int i = 0; i < 2; i++)
    #pragma unroll
    for (int j = 0; j < 2; j++)
      #pragma unroll
      for (int r = 0; r < 4; r++) acc[i][j][r] = 0.f;

  int koff = 0;
  #pragma unroll
  for (int kit = 0; kit < NITER; kit++, koff += 192){
    if (kit > 0) __syncthreads();     // prior panel's ds_reads done
    #pragma unroll
    for (int q = 0; q < 6; q++){
      int p = q * 256 + tid;
      int r = p / 24, sp = p - r * 24;
      int sl = sp ^ (r & 7);
      gl16(Ab + (long)(m0 + r) * lda + koff + sl * 8, sA + (q * 256 + wb) * 8);
    }
    #pragma unroll
    for (int q = 0; q < 6; q++){
      int p = q * 256 + tid;
      int r = p / 24, sp = p - r * 24;
      int sl = sp ^ (r & 7);
      gl16(Bb + (long)(n0 + r) * ldb + koff + sl * 8, sB + (q * 256 + wb) * 8);
    }
    __syncthreads();                  // drain gl16 -> LDS ready
    #pragma unroll
    for (int ks = 0; ks < 6; ks++){
      s16x8 af[2], bfr[2];
      #pragma unroll
      for (int i = 0; i < 2; i++){
        int r = wm + i * 16 + lr;
        af[i] = *(const s16x8*)(sA + r * 192 + (((ks * 4 + kg) ^ (r & 7)) * 8));
      }
      #pragma unroll
      for (int j = 0; j < 2; j++){
        int r = wn + j * 16 + lr;
        bfr[j] = *(const s16x8*)(sB + r * 192 + (((ks * 4 + kg) ^ (r & 7)) * 8));
      }
      #pragma unroll
      for (int i = 0; i < 2; i++)
        #pragma unroll
        for (int j = 0; j < 2; j++)
          acc[i][j] = __builtin_amdgcn_mfma_f32_16x16x32_bf16(af[i], bfr[j], acc[i][j], 0, 0, 0);
    }
  }

  long zc = (long)bo * cOuter + (long)bi_ * cInner;
  #pragma unroll
  for (int i = 0; i < 2; i++){
    #pragma unroll
    for (int j = 0; j < 2; j++){
      #pragma unroll
      for (int r = 0; r < 4; r++){
        int m = m0 + wm + i * 16 + kg * 4 + r;
        int n = n0 + wn + j * 16 + lr;
        float v = acc[i][j][r];
        if constexpr (MODE == 1){
          if (n < 192) ((u16*)Cf)[zc + (long)m * 192 + n] = f2bf(v);
          else         Ch[zc + (long)m * 192 + (n - 192)] = f2bf(v * fsigmoid(v));
        } else if constexpr (MODE == 2){
          Ch[zc + (long)m * ldc + n] = f2bf(v);
        } else {
          float vb = v + bias[n];
          long o = (long)m * ldc + n;
          Cf[o] = resid[o] + skip[0] * vb;
        }
      }
    }
  }
}

// ---------------- bf16 MFMA GEMM (legacy, used for MODE 4 / K=32) ----------------
// MODE 4: gate = sigmoid(v+bias[n]); Ch[m*ldc+n] = bf16(gate * bf2f(gy[m*ldc+ginv[(m>>12)*CH+n]]))
template<int BN, int MODE>
__global__ __launch_bounds__(256) void k_mm(
    const u16* __restrict__ A, int lda, long aOuter, long aInner,
    const u16* __restrict__ B, long bInner,
    float* __restrict__ Cf, u16* __restrict__ Ch,
    long cOuter, long cInner, int ldc,
    int K, int innerCnt,
    const float* __restrict__ bias, const float* __restrict__ resid,
    const float* __restrict__ skip,
    const u16* __restrict__ gy, const int* __restrict__ ginv){
  constexpr int BM = 128;
  constexpr int AI = 2;
  constexpr int BI = (BN * 32) / (256 * 8);
  constexpr int NJ = BN / 32;
  __shared__ u16 sA[BM * 32];
  __shared__ u16 sB[BN * 32];

  int bz = blockIdx.z;
  int bo = bz / innerCnt, bi_ = bz - bo * innerCnt;
  const u16* Ab = A + (long)bo * aOuter + (long)bi_ * aInner;
  const u16* Bb = B + (long)bi_ * bInner;
  int tid = threadIdx.x;
  int m0 = blockIdx.y * BM, n0 = blockIdx.x * BN;
  int wv = tid >> 6, l = tid & 63;
  int wm = (wv >> 1) * 64, wn = (wv & 1) * (BN / 2);
  int kg = l >> 4, lr = l & 15;

  f32x4 acc[4][NJ];
  #pragma unroll
  for (int i = 0; i < 4; i++)
    #pragma unroll
    for (int j = 0; j < NJ; j++)
      #pragma unroll
      for (int r = 0; r < 4; r++) acc[i][j][r] = 0.f;

  int aoffU[4], boffU[NJ];
  #pragma unroll
  for (int i = 0; i < 4; i++){
    int r = wm + i * 16 + lr;
    aoffU[i] = r * 32 + ((kg * 8) ^ ((r & 3) << 3));
  }
  #pragma unroll
  for (int j = 0; j < NJ; j++){
    int r = wn + j * 16 + lr;
    boffU[j] = r * 32 + ((kg * 8) ^ ((r & 3) << 3));
  }

  int wb = tid & 192;
  int nks = K >> 5;
  for (int ks = 0; ks < nks; ks++){
    int k0 = ks << 5;
    __syncthreads();
    #pragma unroll
    for (int q = 0; q < AI; q++){
      int i = q * 256 + tid; int row = i >> 2, ss = (i & 3) ^ (row & 3);
      gl16(Ab + (long)(m0 + row) * lda + k0 + ss * 8, sA + (q * 256 + wb) * 8);
    }
    #pragma unroll
    for (int q = 0; q < BI; q++){
      int i = q * 256 + tid; int row = i >> 2, ss = (i & 3) ^ (row & 3);
      gl16(Bb + (long)(n0 + row) * K + k0 + ss * 8, sB + (q * 256 + wb) * 8);
    }
    __syncthreads();
    s16x8 af[4];
    #pragma unroll
    for (int i = 0; i < 4; i++) af[i] = *(const s16x8*)(sA + aoffU[i]);
    s16x8 bfr[NJ];
    #pragma unroll
    for (int j = 0; j < NJ; j++) bfr[j] = *(const s16x8*)(sB + boffU[j]);
    #pragma unroll
    for (int i = 0; i < 4; i++)
      #pragma unroll
      for (int j = 0; j < NJ; j++)
        acc[i][j] = __builtin_amdgcn_mfma_f32_16x16x32_bf16(af[i], bfr[j], acc[i][j], 0, 0, 0);
  }

  long zc = (long)bo * cOuter + (long)bi_ * cInner;
  #pragma unroll
  for (int i = 0; i < 4; i++){
    #pragma unroll
    for (int j = 0; j < NJ; j++){
      #pragma unroll
      for (int r = 0; r < 4; r++){
        int m = m0 + wm + i * 16 + kg * 4 + r;
        int n = n0 + wn + j * 16 + lr;
        float v = acc[i][j][r];
        if constexpr (MODE == 4){
          float gate = fsigmoid(v + bias[n]);
          int bt = m >> 12;
          float yr = bf2f(gy[(long)m * ldc + ginv[bt * CH + n]]);
          Ch[(long)m * ldc + n] = f2bf(yr * gate);
        }
      }
    }
  }
}

// ---------------- fused dt GEMM + chunk-scan (p1), both directions per block ----------------
// grid (3, 64, 16): z = bg. Shares the A tile and xv reads between k=0 and k=1.
// Dual scan buffers: both directions scanned concurrently by half-blocks.
__global__ __launch_bounds__(256) void k_dt(
    const u16* __restrict__ xcvh, const u16* __restrict__ Mw,
    const float* __restrict__ dtb, const float* __restrict__ Atab,
    const float* __restrict__ bc, u16* __restrict__ pk16,
    float* __restrict__ cP, float* __restrict__ cS){
  __shared__ unsigned sMem[2 * 64 * 64];   // 32 KB: staging (12 KB) then 2 scan buffers
  u16* sA  = (u16*)sMem;                   // [0, 4 KB)
  u16* sB0 = (u16*)(sMem + 1024);          // [4, 8 KB)
  u16* sB1 = (u16*)(sMem + 2048);          // [8, 12 KB)

  int bg = blockIdx.z;
  int g = bg & 1;
  int gk0 = g * 2, gk1 = g * 2 + 1;
  const u16* Ab  = xcvh + (long)bg * LTOK * 192;
  const u16* Bb0 = Mw + (long)gk0 * 36864;
  const u16* Bb1 = Mw + (long)gk1 * 36864;
  int tid = threadIdx.x;
  int m0 = blockIdx.y * 64, n0 = blockIdx.x * 64;
  int wv = tid >> 6, l = tid & 63;
  int wm = (wv >> 1) * 32, wn = (wv & 1) * 32;
  int kg = l >> 4, lr = l & 15;

  f32x4 acc0[2][2], acc1[2][2];
  #pragma unroll
  for (int i = 0; i < 2; i++)
    #pragma unroll
    for (int j = 0; j < 2; j++)
      #pragma unroll
      for (int r = 0; r < 4; r++){ acc0[i][j][r] = 0.f; acc1[i][j][r] = 0.f; }

  int aoffU[2], boffU[2];
  #pragma unroll
  for (int i = 0; i < 2; i++){
    int r = wm + i * 16 + lr;
    aoffU[i] = r * 32 + ((kg * 8) ^ ((r & 3) << 3));
  }
  #pragma unroll
  for (int j = 0; j < 2; j++){
    int r = wn + j * 16 + lr;
    boffU[j] = r * 32 + ((kg * 8) ^ ((r & 3) << 3));
  }

  int srow = tid >> 2, sss = (tid & 3) ^ (srow & 3);
  int wb = tid & 192;
  const int nks = 6;   // K = 192
  for (int ks = 0; ks < nks; ks++){
    int k0 = ks << 5;
    __syncthreads();
    gl16(Ab  + (long)(m0 + srow) * 192 + k0 + sss * 8, sA  + wb * 8);
    gl16(Bb0 + (long)(n0 + srow) * 192 + k0 + sss * 8, sB0 + wb * 8);
    gl16(Bb1 + (long)(n0 + srow) * 192 + k0 + sss * 8, sB1 + wb * 8);
    __syncthreads();
    s16x8 af[2], b0[2], b1[2];
    #pragma unroll
    for (int i = 0; i < 2; i++) af[i] = *(const s16x8*)(sA + aoffU[i]);
    #pragma unroll
    for (int j = 0; j < 2; j++){ b0[j] = *(const s16x8*)(sB0 + boffU[j]);
                                 b1[j] = *(const s16x8*)(sB1 + boffU[j]); }
    #pragma unroll
    for (int i = 0; i < 2; i++)
      #pragma unroll
      for (int j = 0; j < 2; j++){
        acc0[i][j] = __builtin_amdgcn_mfma_f32_16x16x32_bf16(af[i], b0[j], acc0[i][j], 0, 0, 0);
        acc1[i][j] = __builtin_amdgcn_mfma_f32_16x16x32_bf16(af[i], b1[j], acc1[i][j], 0, 0, 0);
      }
  }

  // epilogue: both directions; one scattered xv read shared
  unsigned pk0[2][2][4], pk1[2][2][4];
  float dtb0[2], Atl0[2], dtb1[2], Atl1[2];
  #pragma unroll
  for (int j = 0; j < 2; j++){
    int n = n0 + wn + j * 16 + lr;
    dtb0[j] = dtb[gk0 * 192 + n];  Atl0[j] = Atab[gk0 * 192 + n];
    dtb1[j] = dtb[gk1 * 192 + n];  Atl1[j] = Atab[gk1 * 192 + n];
  }
  #pragma unroll
  for (int i = 0; i < 2; i++){
    #pragma unroll
    for (int r = 0; r < 4; r++){
      int ml = wm + i * 16 + kg * 4 + r;
      int m = m0 + ml;
      long rowz0 = ((long)bg * 2) * LTOK + m;
      long rowz1 = rowz0 + LTOK;
      long rowx  = (long)bg * LTOK + m;
      float Bv0 = bc[rowz0 * 2], Bv1 = bc[rowz1 * 2];
      float d0s[2], d1s[2];
      #pragma unroll
      for (int j = 0; j < 2; j++){
        int n = n0 + wn + j * 16 + lr;
        float xv = bf2f(xcvh[rowx * 192 + n]);
        float r0 = acc0[i][j][r] + dtb0[j];
        float t0 = __logf(1.f + __expf(r0));
        float a0 = __expf(Atl0[j] * t0);
        float r1 = acc1[i][j][r] + dtb1[j];
        float t1 = __logf(1.f + __expf(r1));
        float a1 = __expf(Atl1[j] * t1);
        d0s[j] = t0; d1s[j] = t1;
        pk0[i][j][r] = cvt_pk_bf16(a0, t0 * Bv0 * xv);
        pk1[i][j][r] = cvt_pk_bf16(a1, t1 * Bv1 * xv);
      }
      unsigned p0 = cvt_pk_bf16(d0s[0], d0s[1]);
      pk16[rowz0 * 192 + n0 + wn + lr]      = (u16)(p0 & 0xFFFFu);
      pk16[rowz0 * 192 + n0 + wn + 16 + lr] = (u16)(p0 >> 16);
      unsigned p1 = cvt_pk_bf16(d1s[0], d1s[1]);
      pk16[rowz1 * 192 + n0 + wn + lr]      = (u16)(p1 & 0xFFFFu);
      pk16[rowz1 * 192 + n0 + wn + 16 + lr] = (u16)(p1 >> 16);
    }
  }

  // write both packed buffers, one barrier, dual-parallel scan
  __syncthreads();
  #pragma unroll
  for (int i = 0; i < 2; i++)
    #pragma unroll
    for (int j = 0; j < 2; j++)
      #pragma unroll
      for (int r = 0; r < 4; r++){
        int ml = wm + i * 16 + kg * 4 + r;
        int cl = wn + j * 16 + lr;
        sMem[ml * 64 + SCOL(ml, cl)]        = pk0[i][j][r];
        sMem[4096 + ml * 64 + SCOL(ml, cl)] = pk1[i][j][r];
      }
  __syncthreads();
  {
    int dir = tid >> 7;            // 0: forward (k=0), 1: reverse (k=1)
    int t2 = tid & 127;
    int cc = t2 >> 6, nn = t2 & 63;
    const unsigned* buf = sMem + dir * 4096;
    float P = 1.f, S = 0.f;
    if (dir == 0){
      for (int s = 0; s < CHS; s++){
        int row = cc * CHS + s;
        unsigned v = buf[row * 64 + SCOL(row, nn)];
        float a = bf2f((u16)(v & 0xFFFFu));
        float dBx = bf2f((u16)(v >> 16));
        P *= a; S = a * S + dBx;
      }
    } else {
      for (int s = CHS - 1; s >= 0; s--){
        int row = cc * CHS + s;
        unsigned v = buf[row * 64 + SCOL(row, nn)];
        float a = bf2f((u16)(v & 0xFFFFu));
        float dBx = bf2f((u16)(v >> 16));
        P *= a; S = a * S + dBx;
      }
    }
    int cglob = (dir == 0) ? (blockIdx.y * 2 + cc)
                           : (NCHK - 1 - blockIdx.y * 2 - cc);
    long idx = (((long)bg * 2 + dir) * NCHK + cglob) * 192 + n0 + nn;
    cP[idx] = P;
    cS[idx] = S;
  }
}

// ---------------- depthwise 3x3 conv (u16x8/thread) + fused B/C projection ----------------
__global__ __launch_bounds__(192) void k_conv(const u16* __restrict__ xch,
    const u16* __restrict__ cwb, const float* __restrict__ cb,
    const float* __restrict__ xpw, u16* __restrict__ xcvh,
    float* __restrict__ bc){
  __shared__ float red[8][4][25];
  int tid = threadIdx.x;
  int chg = tid % 24, pp = tid / 24;    // 24 channel-groups x 8 positions
  int p = blockIdx.x * 8 + pp;
  int bg = blockIdx.y; int g = bg & 1;
  int h = p >> 6, w = p & 63;
  int di = chg * 8;
  long sb = (long)bg * LTOK;

  u16x8 wv[9];
  #pragma unroll
  for (int t = 0; t < 9; t++)
    wv[t] = *(const u16x8*)(cwb + ((long)g * 9 + t) * DH + di);

  float acc[8];
  #pragma unroll
  for (int j = 0; j < 8; j++) acc[j] = cb[g * DH + di + j];

  #pragma unroll
  for (int dh = -1; dh <= 1; dh++){
    int hh = h + dh; if (hh < 0 || hh >= HH) continue;
    #pragma unroll
    for (int dw = -1; dw <= 1; dw++){
      int ww2 = w + dw; if (ww2 < 0 || ww2 >= WW) continue;
      u16x8 xv = *(const u16x8*)(xch + (sb + hh * WW + ww2) * DH + di);
      int t = (dh + 1) * 3 + (dw + 1);
      #pragma unroll
      for (int j = 0; j < 8; j++) acc[j] += bf2f(wv[t][j]) * bf2f(xv[j]);
    }
  }

  u16x8 ov;
  #pragma unroll
  for (int j = 0; j < 8; j++){
    float s = acc[j];
    acc[j] = s * fsigmoid(s);         // post-silu fp32, reused for B/C dot
    ov[j] = f2bf(acc[j]);
  }
  int lscan = (g == 0) ? p : (w * HH + h);
  *(u16x8*)(xcvh + (sb + lscan) * DH + di) = ov;

  // B/C projection partials
  #pragma unroll
  for (int j = 0; j < 4; j++){
    int k = j >> 1, ci = j & 1;
    const float* wl = xpw + (long)g * 5376 + (k * 14 + 12 + ci) * 192 + di;
    float sacc = 0.f;
    #pragma unroll
    for (int q = 0; q < 8; q++) sacc += acc[q] * wl[q];
    red[pp][j][chg] = sacc;
  }
  __syncthreads();
  if (tid < 32){
    int pos = tid >> 2, j = tid & 3;
    float ssum = 0.f;
    #pragma unroll
    for (int q = 0; q < 24; q++) ssum += red[pos][j][q];
    int p2 = blockIdx.x * 8 + pos;
    int h2 = p2 >> 6, w2 = p2 & 63;
    int ls = (g == 0) ? p2 : (w2 * HH + h2);
    int k = j >> 1;
    bc[(((long)(bg * 2 + k)) * LTOK + ls) * 2 + (j & 1)] = ssum;
  }
}

// ---------------- scan p2: sequential composition over 128 chunks ----------------
__global__ __launch_bounds__(192) void k_scan_p2(const float* __restrict__ cP,
    const float* __restrict__ cS, float* __restrict__ h0){
  int z = blockIdx.x;              // 0..31
  int di = threadIdx.x;
  float h = 0.f;
  for (int c = 0; c < NCHK; c++){
    long idx = ((long)z * NCHK + c) * 192 + di;
    h0[idx] = h;
    h = cP[idx] * h + cS[idx];
  }
}

// ---------------- scan p3 fused: both directions in regs + out-LN + *siluz -> yab ----------------
__global__ __launch_bounds__(192) void k_scan_p3(const u16* __restrict__ pk16,
    const u16* __restrict__ xcvh, const float* __restrict__ bc,
    const float* __restrict__ Atab, const float* __restrict__ ds,
    const float* __restrict__ h0, const u16* __restrict__ zsh,
    const float* __restrict__ ong, const float* __restrict__ onb,
    u16* __restrict__ yab){
  __shared__ float yl[CHS][193];
  __shared__ float red[2][32][6];
  __shared__ float minv[2][32];
  int bg = blockIdx.x, c = blockIdx.y;
  int g = bg & 1;
  int di = threadIdx.x;
  const u16* xc = xcvh + (long)bg * LTOK * 192 + di;
  int l0 = c * CHS;
  float yv[CHS];

  // forward direction (k=0)
  {
    int z = bg * 2, gk = g * 2;
    float Dv = ds[gk * 192 + di], Av = Atab[gk * 192 + di];
    const u16* pk = pk16 + (long)z * LTOK * 192 + di;
    const float* bcp = bc + (long)z * LTOK * 2;
    float h = h0[((long)z * NCHK + c) * 192 + di];
    #pragma unroll
    for (int s = 0; s < CHS; s++){
      int l = l0 + s;
      float dtv = bf2f(pk[(long)l * 192]);
      float av  = __expf(Av * dtv);
      float xv  = bf2f(xc[(long)l * 192]);
      float Bv  = bcp[l * 2], Cv = bcp[l * 2 + 1];
      h = av * h + dtv * Bv * xv;
      yv[s] = h * Cv + Dv * xv;
    }
  }
  // backward direction (k=1) covers the same positions
  {
    int z = bg * 2 + 1, gk = g * 2 + 1;
    float Dv = ds[gk * 192 + di], Av = Atab[gk * 192 + di];
    const u16* pk = pk16 + (long)z * LTOK * 192 + di;
    const float* bcp = bc + (long)z * LTOK * 2;
    int cc = NCHK - 1 - c;
    float h = h0[((long)z * NCHK + cc) * 192 + di];
    #pragma unroll
    for (int s = CHS - 1; s >= 0; s--){
      int l = l0 + s;
      float dtv = bf2f(pk[(long)l * 192]);
      float av  = __expf(Av * dtv);
      float xv  = bf2f(xc[(long)l * 192]);
      float Bv  = bcp[l * 2], Cv = bcp[l * 2 + 1];
      h = av * h + dtv * Bv * xv;
      yv[s] += h * Cv + Dv * xv;
    }
  }

  // out-LN across channels per position (192 threads = all channels)
  #pragma unroll
  for (int s = 0; s < CHS; s++) yl[s][di] = yv[s];
  __syncthreads();
  {
    int pos = di & 31, seg = di >> 5;
    float s1 = 0.f, s2 = 0.f;
    #pragma unroll
    for (int q = 0; q < 32; q++){
      float v = yl[pos][seg * 32 + q];
      s1 += v; s2 += v * v;
    }
    red[0][pos][seg] = s1;
    red[1][pos][seg] = s2;
  }
  __syncthreads();
  if (di < 32){
    float s1 = 0.f, s2 = 0.f;
    #pragma unroll
    for (int q = 0; q < 6; q++){ s1 += red[0][di][q]; s2 += red[1][di][q]; }
    float m = s1 * (1.f / DH);
    float var = s2 * (1.f / DH) - m * m;
    minv[0][di] = m;
    minv[1][di] = rsqrtf(var + 1e-5f);
  }
  __syncthreads();

  float gng = ong[g * 192 + di], gnb = onb[g * 192 + di];
  long zbase = (long)bg * LTOK;
  #pragma unroll
  for (int s = 0; s < CHS; s++){
    int l = l0 + s;
    int p = (g == 0) ? l : ((l & 63) * 64 + (l >> 6));
    float m = minv[0][s], inv = minv[1][s];
    float yln = (yv[s] - m) * inv * gng + gnb;
    float zs = bf2f(zsh[(zbase + p) * 192 + di]);   // pre-silu'd z
    yab[(zbase + p) * 192 + di] = f2bf(yln * zs);
  }
}

extern "C" void kernel_launch(void* const* d_in, const int* in_sizes, int n_in,
                              void* d_out, int out_size, void* d_ws, size_t ws_size,
                              hipStream_t stream){
  const float* x       = (const float*)d_in[0];
  const float* norm_g  = (const float*)d_in[1];
  const float* norm_b  = (const float*)d_in[2];
  const float* r_w1    = (const float*)d_in[3];
  const float* r_b1    = (const float*)d_in[4];
  const float* r_w2    = (const float*)d_in[5];
  const float* r_b2    = (const float*)d_in[6];
  const float* in_proj = (const float*)d_in[7];
  const float* conv_w  = (const float*)d_in[8];
  const float* conv_b  = (const float*)d_in[9];
  const float* xp_w    = (const float*)d_in[10];
  const float* dt_w    = (const float*)d_in[11];
  const float* dt_b    = (const float*)d_in[12];
  const float* A_log   = (const float*)d_in[13];
  const float* Ds      = (const float*)d_in[14];
  const float* on_g    = (const float*)d_in[15];
  const float* on_b    = (const float*)d_in[16];
  const float* op_w    = (const float*)d_in[17];
  const float* ci_w1   = (const float*)d_in[18];
  const float* ci_b1   = (const float*)d_in[19];
  const float* ci_w2   = (const float*)d_in[20];
  const float* ci_b2   = (const float*)d_in[21];
  const float* proj_w  = (const float*)d_in[22];
  const float* proj_b  = (const float*)d_in[23];
  const float* skip    = (const float*)d_in[24];
  float* out = (float*)d_out;
  float* ws  = (float*)d_ws;

  // Regions (floats):
  // R1 = ws[0 .. BLC)         : mst stats (front-end) -> pk16 u16 (k_dt onward)
  // R2 = [BLC .. 2*BLC)       : xcbh bf16 -> gab bf16
  // R3 = [2*BLC .. 2.5*BLC)   : zsh bf16 -> ycat bf16
  // R4 = [2.5B .. 3*BLC)      : xcvh bf16
  // R5 = [3*BLC .. 3.5*BLC)   : As bf16 -> yab bf16
  float* mst  = ws;                      // 2 floats per token (m, inv); dead before pk16
  float* xcb  = ws + BLC;
  float* R3   = ws + 2 * BLC;
  float* R4   = R3 + BLC / 2;
  float* R5   = R4 + BLC / 2;
  float* pp   = R5 + BLC / 2;
  int*  sidx  = (int*)(pp + NB * 16 * CH);
  int*  inv   = sidx + NB * CH;
  u16*  wip   = (u16*)(inv + NB * CH);   // 2*384*192
  u16*  wop   = wip + 2 * 384 * 192;     // 2*192*192
  u16*  wpj   = wop + 2 * 192 * 192;     // 384*384
  u16*  w1g   = wpj + 384 * 384;         // NB*32*384
  u16*  w2p   = w1g + NB * 32 * CH;      // 384*32
  u16*  Mw    = w2p + CH * 32;           // 4*192*192
  u16*  cwb   = Mw + 4 * 192 * 192;      // 2*9*192
  float* b1p  = (float*)(cwb + 2 * 9 * DH);
  float* Atab = b1p + 32;                // 4*192
  u16*  hidp  = (u16*)(Atab + 4 * 192);  // NB*4096*32
  float* bc   = (float*)(hidp + (long)NB * LTOK * 32);  // 32*4096*2
  float* cP   = bc + 32 * LTOK * 2;
  float* cS   = cP + CST;
  float* h0   = cS + CST;

  size_t need = ((size_t)(2 * BLC) + 3 * (BLC / 2) + NB * 16 * CH + 32 * LTOK * 2 + 3 * CST + 64) * 4
              + (size_t)(2 * NB * CH) * 4 + (size_t)(4 * 192 + 32) * 4
              + ((size_t)2*384*192 + 2*192*192 + 384*384 + NB*32*CH + CH*32 + 4*192*192
                 + 2*9*DH + (size_t)NB * LTOK * 32) * 2
              + 8192;
  if (ws_size < need) return;

  // aliases
  u16*  As   = (u16*)R5;
  u16*  zsh  = (u16*)R3;                // silu(z) bf16
  u16*  xcbh = (u16*)xcb;               // bf16 conv input (R2)
  u16*  xcvh = (u16*)R4;
  u16*  pk16 = (u16*)ws;                // bf16 dt stash in R1 (mst dead after castgather)
  u16*  yab  = (u16*)R5;                // As dead after k_hid
  u16*  ycat = (u16*)R3;                // zsh dead after fused p3
  u16*  gab  = (u16*)xcb;               // R2, xcbh dead after conv

  k_lnstat<<<NB * LTOK, 128, 0, stream>>>(x, mst);
  k_preps<<<2033, 256, 0, stream>>>(in_proj, op_w, proj_w, A_log, conv_w,
                                    dt_w, xp_w, wip, wop, wpj, Atab, cwb, Mw);
  k_pool<<<dim3(3, 16, NB), 128, 0, stream>>>(x, mst, norm_g, norm_b, pp);
  k_score<<<NB, 384, 0, stream>>>(pp, r_w1, r_b1, r_w2, r_b2, sidx, inv);
  k_castgather<<<NB * LTOK, 384, 0, stream>>>(x, mst, sidx, norm_g, norm_b, As);
  k_prepw<<<NB + 1, 256, 0, stream>>>(ci_w1, ci_b1, ci_w2, sidx, w1g, w2p, b1p);

  // in_proj: per (b,g): [4096x192]@[384x192]^T -> xcbh bf16 + zsh=silu(z) bf16
  k_mm2<1, 1><<<dim3(6, 64, 16), 256, 0, stream>>>(
      As, CH, (long)LTOK * CH, 192,
      wip, 192, (long)384 * 192,
      (float*)xcbh, zsh, (long)2 * LTOK * DH, (long)LTOK * DH, 0,
      2, nullptr, nullptr, nullptr);

  // gate stage 1 (uses As; before R5 is recycled as yab)
  k_hid<<<dim3(32, NB), 256, 0, stream>>>(As, w1g, b1p, hidp);

  // conv + fused B/C projection
  k_conv<<<dim3(LTOK / 8, NB * 2), 192, 0, stream>>>(xcbh, cwb, conv_b, xp_w, xcvh, bc);

  // fused dt GEMM + chunk scan (p1), both directions per block -> pk16 + cP/cS
  k_dt<<<dim3(3, 64, 16), 256, 0, stream>>>(xcvh, Mw, dt_b, Atab, bc, pk16, cP, cS);

  k_scan_p2<<<32, 192, 0, stream>>>(cP, cS, h0);

  // fused p3: both directions + out-LN + *silu(z) -> yab
  k_scan_p3<<<dim3(NB * 2, NCHK), 192, 0, stream>>>(
      pk16, xcvh, bc, Atab, Ds, h0, zsh, on_g, on_b, yab);

  // out_proj: per (b,g): [4096x192]@[192x192]^T -> ycat bf16 (col offset g*192)
  k_mm2<1, 2><<<dim3(3, 64, 16), 256, 0, stream>>>(
      yab, DH, (long)2 * LTOK * DH, (long)LTOK * DH,
      wop, 192, (long)192 * 192,
      nullptr, ycat, (long)LTOK * CH, 192, CH,
      2, nullptr, nullptr, nullptr);

  // gate stage 2 + un-sort gather + multiply
  k_mm<128, 4><<<dim3(3, 256, 1), 256, 0, stream>>>(
      hidp, 32, 0, 0,
      w2p, 0,
      nullptr, gab, 0, 0, CH,
      32, 1, ci_b2, nullptr, nullptr, ycat, inv);

  // final: out = x + skip * (gab @ proj_w^T + proj_b)
  k_mm2<2, 3><<<dim3(6, 512, 1), 256, 0, stream>>>(
      gab, CH, 0, 0,
      wpj, 384, 0,
      out, nullptr, 0, 0, CH,
      1, proj_b, x, skip);
}

// Round 24
// 340.296 us; speedup vs baseline: 1.0679x; 1.0679x over previous
//
#include <hip/hip_runtime.h>
#include <math.h>

// Problem constants (fixed by the reference module)
#define NB 8
#define LTOK 4096
#define CH 384
#define DH 192
#define HH 64
#define WW 64
#define NCHK 128     // chunks per sequence
#define CHS 32       // steps per chunk (LTOK / NCHK)

static constexpr long BLC  = (long)NB * LTOK * CH;   // 12,582,912 elements
static constexpr long CST  = (long)32 * NCHK * DH;   // 786,432 per chunk-state buffer

typedef unsigned short u16;
typedef u16   u16x8 __attribute__((ext_vector_type(8)));
typedef short s16x8 __attribute__((ext_vector_type(8)));
typedef float f32x4 __attribute__((ext_vector_type(4)));

__device__ inline u16 f2bf(float f){
  unsigned int u = __float_as_uint(f);
  return (u16)((u + 0x7FFFu + ((u >> 16) & 1u)) >> 16);
}
__device__ inline float bf2f(u16 h){ return __uint_as_float(((unsigned int)h) << 16); }
__device__ inline float fsigmoid(float x){ return 1.f / (1.f + __expf(-x)); }
// pack two f32 -> two bf16 in one u32: lo = src0, hi = src1
__device__ inline unsigned cvt_pk_bf16(float lo, float hi){
  unsigned r;
  asm("v_cvt_pk_bf16_f32 %0, %1, %2" : "=v"(r) : "v"(lo), "v"(hi));
  return r;
}
// async global->LDS, 16 B per lane; l must be wave-uniform (HW: base + lane*16)
__device__ inline void gl16(const u16* g, u16* l){
  __builtin_amdgcn_global_load_lds(
      (const __attribute__((address_space(1))) void*)g,
      (__attribute__((address_space(3))) void*)l, 16, 0, 0);
}

// LDS scan-buffer column swizzle: spreads kg-lanes across banks (2-way max)
#define SCOL(ml, c) ((c) ^ ((((ml) >> 2) & 3) << 4))

template<int NW>
__device__ inline float blockSum(float v, float* sm){
  #pragma unroll
  for (int o = 32; o > 0; o >>= 1) v += __shfl_down(v, o);
  int lane = threadIdx.x & 63, wv = threadIdx.x >> 6;
  if (lane == 0) sm[wv] = v;
  __syncthreads();
  if (threadIdx.x == 0){ float t = 0.f; for (int i = 0; i < NW; i++) t += sm[i]; sm[0] = t; }
  __syncthreads();
  float t = sm[0];
  __syncthreads();
  return t;
}

// ---------------- LayerNorm over C=384 per token ----------------
__global__ __launch_bounds__(128) void k_ln(const float* __restrict__ x,
    const float* __restrict__ g, const float* __restrict__ b, float* __restrict__ xn){
  __shared__ float sm[2];
  long row = blockIdx.x;
  int t = threadIdx.x;
  const float* xr = x + row * CH;
  float v0 = xr[t], v1 = xr[t + 128], v2 = xr[t + 256];
  float s = blockSum<2>(v0 + v1 + v2, sm);
  float m = s * (1.f / CH);
  float d0 = v0 - m, d1 = v1 - m, d2 = v2 - m;
  float vs = blockSum<2>(d0*d0 + d1*d1 + d2*d2, sm);
  float inv = rsqrtf(vs * (1.f / CH) + 1e-5f);
  float* o = xn + row * CH;
  o[t]       = d0 * inv * g[t]       + b[t];
  o[t + 128] = d1 * inv * g[t + 128] + b[t + 128];
  o[t + 256] = d2 * inv * g[t + 256] + b[t + 256];
}

// ---------------- partial pooling ----------------
__global__ __launch_bounds__(128) void k_pool(const float* __restrict__ xn, float* __restrict__ pp){
  int c = blockIdx.x * 128 + threadIdx.x;
  int chunk = blockIdx.y, b = blockIdx.z;
  long base = ((long)b * LTOK + chunk * 256) * CH;
  float s = 0.f;
  for (int n = 0; n < 256; n++) s += xn[base + (long)n * CH + c];
  pp[((long)b * 16 + chunk) * CH + c] = s;
}

// ---------------- score MLP + stable argsort (descending) ----------------
__global__ __launch_bounds__(384) void k_score(const float* __restrict__ pp,
    const float* __restrict__ w1, const float* __restrict__ b1,
    const float* __restrict__ w2, const float* __restrict__ b2,
    int* __restrict__ sidx, int* __restrict__ inv){
  __shared__ float poolv[CH];
  __shared__ float hid[192];
  __shared__ float sc[CH];
  int b = blockIdx.x, t = threadIdx.x;
  float s = 0.f;
  for (int ch = 0; ch < 16; ch++) s += pp[((long)b * 16 + ch) * CH + t];
  poolv[t] = s * (1.f / LTOK);
  __syncthreads();
  if (t < 192){
    float h = b1[t];
    for (int c = 0; c < CH; c++) h += poolv[c] * w1[t * CH + c];
    hid[t] = fmaxf(h, 0.f);
  }
  __syncthreads();
  {
    float h = b2[t];
    for (int j = 0; j < 192; j++) h += hid[j] * w2[t * 192 + j];
    sc[t] = 1.f / (1.f + expf(-h));
  }
  __syncthreads();
  float mys = sc[t];
  int rank = 0;
  for (int j = 0; j < CH; j++){
    float o = sc[j];
    rank += (o > mys) || (o == mys && j < t);
  }
  sidx[b * CH + rank] = t;
  inv[b * CH + t] = rank;
}

// ---------------- merged prep: weight casts + Atab + conv-w transpose + fused dt M ----------------
__global__ __launch_bounds__(256) void k_preps(const float* __restrict__ in_proj,
    const float* __restrict__ op_w, const float* __restrict__ proj_w,
    const float* __restrict__ alog, const float* __restrict__ cw,
    const float* __restrict__ dtw, const float* __restrict__ xpw,
    u16* __restrict__ wip, u16* __restrict__ wop, u16* __restrict__ wpj,
    float* __restrict__ Atab, u16* __restrict__ cwb, u16* __restrict__ Mw){
  const int N1 = 2*384*192;        // wip
  const int N2 = N1 + 2*192*192;   // wop
  const int N3 = N2 + 384*384;     // wpj
  const int N4 = N3 + 4*192;       // Atab
  const int N5 = N4 + 2*9*DH;      // cwb
  const int N6 = N5 + 4*36864;     // Mw
  int i = blockIdx.x * 256 + threadIdx.x;
  if (i < N1)      wip[i] = f2bf(in_proj[i]);
  else if (i < N2) wop[i-N1] = f2bf(op_w[i-N1]);
  else if (i < N3) wpj[i-N2] = f2bf(proj_w[i-N2]);
  else if (i < N4) Atab[i-N3] = -expf(alog[i-N3]);
  else if (i < N5){
    int r = i - N4;
    int g = r / (9*DH); int r2 = r - g*9*DH;
    int tap = r2 / DH, di = r2 - tap*DH;
    cwb[r] = f2bf(cw[((long)g*DH + di)*9 + tap]);
  } else if (i < N6){
    int r = i - N5;
    int gk = r / 36864; int idx = r - gk * 36864;
    int g = gk >> 1, k = gk & 1;
    int di = idx / 192, c = idx - di * 192;
    float s = 0.f;
    #pragma unroll
    for (int q = 0; q < 12; q++)
      s += dtw[((long)gk * 192 + di) * 12 + q] * xpw[(long)g * 5376 + (k * 14 + q) * 192 + c];
    Mw[(long)gk * 36864 + idx] = f2bf(s);
  }
}

// ---------------- gather sorted channels + cast to bf16 ----------------
__global__ __launch_bounds__(384) void k_castgather(const float* __restrict__ xn,
    const int* __restrict__ sidx, u16* __restrict__ As){
  long row = blockIdx.x;
  int b = (int)(row >> 12);
  int t = threadIdx.x;
  int c = sidx[b * CH + t];
  As[row * CH + t] = f2bf(xn[row * CH + c]);
}

// ---------------- prep gate-MLP weights: gathered w1 (per batch), padded w2, b1 ----------------
__global__ __launch_bounds__(256) void k_prepw(const float* __restrict__ w1,
    const float* __restrict__ b1, const float* __restrict__ w2,
    const int* __restrict__ sidx, u16* __restrict__ w1g, u16* __restrict__ w2p,
    float* __restrict__ b1p){
  int b = blockIdx.x, tid = threadIdx.x;
  if (b < NB){
    const int* sx = sidx + b * CH;
    for (int i = tid; i < 32 * CH; i += 256){
      int j = i / CH, r = i - j * CH;
      float v = (j < 24) ? w1[j * CH + sx[r]] : 0.f;
      w1g[(long)b * 32 * CH + i] = f2bf(v);
    }
  } else {
    for (int i = tid; i < CH * 32; i += 256){
      int n = i >> 5, j = i & 31;
      w2p[i] = f2bf((j < 24) ? w2[n * 24 + j] : 0.f);
    }
    if (tid < 32) b1p[tid] = (tid < 24) ? b1[tid] : 0.f;
  }
}

// ---------------- gate stage 1: hid = relu(As @ w1g^T + b1p), bf16 out ----------------
__global__ __launch_bounds__(256) void k_hid(const u16* __restrict__ As,
    const u16* __restrict__ w1g, const float* __restrict__ b1p,
    u16* __restrict__ hidp){
  __shared__ u16 sA[128 * 32];
  __shared__ u16 sB[32 * 32];
  int b = blockIdx.y;
  const u16* Ab = As + (long)b * LTOK * CH;
  const u16* Bb = w1g + (long)b * 32 * CH;
  int tid = threadIdx.x;
  int m0 = blockIdx.x * 128;
  int wv = tid >> 6, l = tid & 63;
  int wm = wv * 32;
  int kg = l >> 4, lr = l & 15;

  f32x4 acc[2][2];
  #pragma unroll
  for (int i = 0; i < 2; i++)
    #pragma unroll
    for (int j = 0; j < 2; j++)
      #pragma unroll
      for (int r = 0; r < 4; r++) acc[i][j][r] = 0.f;

  int aoffU[2], boffU[2];
  #pragma unroll
  for (int i = 0; i < 2; i++){
    int r = wm + i * 16 + lr;
    aoffU[i] = r * 32 + ((kg * 8) ^ ((r & 3) << 3));
  }
  #pragma unroll
  for (int j = 0; j < 2; j++){
    int r = j * 16 + lr;
    boffU[j] = r * 32 + ((kg * 8) ^ ((r & 3) << 3));
  }

  u16x8 ra[2], rbv;
  #pragma unroll
  for (int q = 0; q < 2; q++){
    int i = q * 256 + tid; int row = i >> 2, sl = i & 3, ss = sl ^ (row & 3);
    ra[q] = *(const u16x8*)(Ab + (long)(m0 + row) * CH + ss * 8);
  }
  if (tid < 128){
    int row = tid >> 2, sl = tid & 3, ss = sl ^ (row & 3);
    rbv = *(const u16x8*)(Bb + (long)row * CH + ss * 8);
  }

  const int nks = CH / 32;   // 12
  for (int ks = 0; ks < nks; ks++){
    __syncthreads();
    #pragma unroll
    for (int q = 0; q < 2; q++){
      int i = q * 256 + tid; int row = i >> 2, sl = i & 3;
      *(u16x8*)(sA + row * 32 + sl * 8) = ra[q];
    }
    if (tid < 128){
      int row = tid >> 2, sl = tid & 3;
      *(u16x8*)(sB + row * 32 + sl * 8) = rbv;
    }
    __syncthreads();
    if (ks + 1 < nks){
      int k0 = (ks + 1) * 32;
      #pragma unroll
      for (int q = 0; q < 2; q++){
        int i = q * 256 + tid; int row = i >> 2, sl = i & 3, ss = sl ^ (row & 3);
        ra[q] = *(const u16x8*)(Ab + (long)(m0 + row) * CH + k0 + ss * 8);
      }
      if (tid < 128){
        int row = tid >> 2, sl = tid & 3, ss = sl ^ (row & 3);
        rbv = *(const u16x8*)(Bb + (long)row * CH + k0 + ss * 8);
      }
    }
    s16x8 af[2], bfr[2];
    #pragma unroll
    for (int i = 0; i < 2; i++) af[i] = *(const s16x8*)(sA + aoffU[i]);
    #pragma unroll
    for (int j = 0; j < 2; j++) bfr[j] = *(const s16x8*)(sB + boffU[j]);
    #pragma unroll
    for (int i = 0; i < 2; i++)
      #pragma unroll
      for (int j = 0; j < 2; j++)
        acc[i][j] = __builtin_amdgcn_mfma_f32_16x16x32_bf16(af[i], bfr[j], acc[i][j], 0, 0, 0);
  }

  #pragma unroll
  for (int i = 0; i < 2; i++)
    #pragma unroll
    for (int j = 0; j < 2; j++)
      #pragma unroll
      for (int r = 0; r < 4; r++){
        int m = m0 + wm + i * 16 + kg * 4 + r;
        int n = j * 16 + lr;
        float v = fmaxf(acc[i][j][r] + b1p[n], 0.f);
        hidp[((long)b * LTOK + m) * 32 + n] = f2bf(v);
      }
}

// ---------------- full-K staged bf16 MFMA GEMM: C = A @ B^T ----------------
// BM=BN=64; K staged in NITER panels of 192 (one barrier per panel).
// MODE 1: n<192 -> ((u16*)Cf) bf16 [m*192+n]; n>=192 -> Ch bf16 silu(v)
// MODE 2: Ch bf16 [zc + m*ldc + n]
// MODE 3: Cf fp32 = resid + skip*(v + bias[n])
template<int NITER, int MODE>
__global__ __launch_bounds__(256) void k_mm2(
    const u16* __restrict__ A, int lda, long aOuter, long aInner,
    const u16* __restrict__ B, int ldb, long bInner,
    float* __restrict__ Cf, u16* __restrict__ Ch,
    long cOuter, long cInner, int ldc,
    int innerCnt,
    const float* __restrict__ bias, const float* __restrict__ resid,
    const float* __restrict__ skip){
  __shared__ u16 sA[64 * 192];
  __shared__ u16 sB[64 * 192];

  int bz = blockIdx.z;
  int bo = bz / innerCnt, bi_ = bz - bo * innerCnt;
  const u16* Ab = A + (long)bo * aOuter + (long)bi_ * aInner;
  const u16* Bb = B + (long)bi_ * bInner;
  int tid = threadIdx.x;
  int m0 = blockIdx.y * 64, n0 = blockIdx.x * 64;
  int wv = tid >> 6, l = tid & 63;
  int wm = (wv >> 1) * 32, wn = (wv & 1) * 32;
  int kg = l >> 4, lr = l & 15;
  int wb = tid & 192;                 // wave-uniform lane-block base (slot units)

  f32x4 acc[2][2];
  #pragma unroll
  for (int i = 0; i < 2; i++)
    #pragma unroll
    for (int j = 0; j < 2; j++)
      #pragma unroll
      for (int r = 0; r < 4; r++) acc[i][j][r] = 0.f;

  int koff = 0;
  #pragma unroll
  for (int kit = 0; kit < NITER; kit++, koff += 192){
    if (kit > 0) __syncthreads();     // prior panel's ds_reads done
    #pragma unroll
    for (int q = 0; q < 6; q++){
      int p = q * 256 + tid;
      int r = p / 24, sp = p - r * 24;
      int sl = sp ^ (r & 7);
      gl16(Ab + (long)(m0 + r) * lda + koff + sl * 8, sA + (q * 256 + wb) * 8);
    }
    #pragma unroll
    for (int q = 0; q < 6; q++){
      int p = q * 256 + tid;
      int r = p / 24, sp = p - r * 24;
      int sl = sp ^ (r & 7);
      gl16(Bb + (long)(n0 + r) * ldb + koff + sl * 8, sB + (q * 256 + wb) * 8);
    }
    __syncthreads();                  // drain gl16 -> LDS ready
    #pragma unroll
    for (int ks = 0; ks < 6; ks++){
      s16x8 af[2], bfr[2];
      #pragma unroll
      for (int i = 0; i < 2; i++){
        int r = wm + i * 16 + lr;
        af[i] = *(const s16x8*)(sA + r * 192 + (((ks * 4 + kg) ^ (r & 7)) * 8));
      }
      #pragma unroll
      for (int j = 0; j < 2; j++){
        int r = wn + j * 16 + lr;
        bfr[j] = *(const s16x8*)(sB + r * 192 + (((ks * 4 + kg) ^ (r & 7)) * 8));
      }
      #pragma unroll
      for (int i = 0; i < 2; i++)
        #pragma unroll
        for (int j = 0; j < 2; j++)
          acc[i][j] = __builtin_amdgcn_mfma_f32_16x16x32_bf16(af[i], bfr[j], acc[i][j], 0, 0, 0);
    }
  }

  long zc = (long)bo * cOuter + (long)bi_ * cInner;
  #pragma unroll
  for (int i = 0; i < 2; i++){
    #pragma unroll
    for (int j = 0; j < 2; j++){
      #pragma unroll
      for (int r = 0; r < 4; r++){
        int m = m0 + wm + i * 16 + kg * 4 + r;
        int n = n0 + wn + j * 16 + lr;
        float v = acc[i][j][r];
        if constexpr (MODE == 1){
          if (n < 192) ((u16*)Cf)[zc + (long)m * 192 + n] = f2bf(v);
          else         Ch[zc + (long)m * 192 + (n - 192)] = f2bf(v * fsigmoid(v));
        } else if constexpr (MODE == 2){
          Ch[zc + (long)m * ldc + n] = f2bf(v);
        } else {
          float vb = v + bias[n];
          long o = (long)m * ldc + n;
          Cf[o] = resid[o] + skip[0] * vb;
        }
      }
    }
  }
}

// ---------------- bf16 MFMA GEMM (legacy, used for MODE 4 / K=32) ----------------
// MODE 4: gate = sigmoid(v+bias[n]); Ch[m*ldc+n] = bf16(gate * bf2f(gy[m*ldc+ginv[(m>>12)*CH+n]]))
template<int BN, int MODE>
__global__ __launch_bounds__(256) void k_mm(
    const u16* __restrict__ A, int lda, long aOuter, long aInner,
    const u16* __restrict__ B, long bInner,
    float* __restrict__ Cf, u16* __restrict__ Ch,
    long cOuter, long cInner, int ldc,
    int K, int innerCnt,
    const float* __restrict__ bias, const float* __restrict__ resid,
    const float* __restrict__ skip,
    const u16* __restrict__ gy, const int* __restrict__ ginv){
  constexpr int BM = 128;
  constexpr int AI = 2;
  constexpr int BI = (BN * 32) / (256 * 8);
  constexpr int NJ = BN / 32;
  __shared__ u16 sA[BM * 32];
  __shared__ u16 sB[BN * 32];

  int bz = blockIdx.z;
  int bo = bz / innerCnt, bi_ = bz - bo * innerCnt;
  const u16* Ab = A + (long)bo * aOuter + (long)bi_ * aInner;
  const u16* Bb = B + (long)bi_ * bInner;
  int tid = threadIdx.x;
  int m0 = blockIdx.y * BM, n0 = blockIdx.x * BN;
  int wv = tid >> 6, l = tid & 63;
  int wm = (wv >> 1) * 64, wn = (wv & 1) * (BN / 2);
  int kg = l >> 4, lr = l & 15;

  f32x4 acc[4][NJ];
  #pragma unroll
  for (int i = 0; i < 4; i++)
    #pragma unroll
    for (int j = 0; j < NJ; j++)
      #pragma unroll
      for (int r = 0; r < 4; r++) acc[i][j][r] = 0.f;

  int aoffU[4], boffU[NJ];
  #pragma unroll
  for (int i = 0; i < 4; i++){
    int r = wm + i * 16 + lr;
    aoffU[i] = r * 32 + ((kg * 8) ^ ((r & 3) << 3));
  }
  #pragma unroll
  for (int j = 0; j < NJ; j++){
    int r = wn + j * 16 + lr;
    boffU[j] = r * 32 + ((kg * 8) ^ ((r & 3) << 3));
  }

  int wb = tid & 192;
  int nks = K >> 5;
  for (int ks = 0; ks < nks; ks++){
    int k0 = ks << 5;
    __syncthreads();
    #pragma unroll
    for (int q = 0; q < AI; q++){
      int i = q * 256 + tid; int row = i >> 2, ss = (i & 3) ^ (row & 3);
      gl16(Ab + (long)(m0 + row) * lda + k0 + ss * 8, sA + (q * 256 + wb) * 8);
    }
    #pragma unroll
    for (int q = 0; q < BI; q++){
      int i = q * 256 + tid; int row = i >> 2, ss = (i & 3) ^ (row & 3);
      gl16(Bb + (long)(n0 + row) * K + k0 + ss * 8, sB + (q * 256 + wb) * 8);
    }
    __syncthreads();
    s16x8 af[4];
    #pragma unroll
    for (int i = 0; i < 4; i++) af[i] = *(const s16x8*)(sA + aoffU[i]);
    s16x8 bfr[NJ];
    #pragma unroll
    for (int j = 0; j < NJ; j++) bfr[j] = *(const s16x8*)(sB + boffU[j]);
    #pragma unroll
    for (int i = 0; i < 4; i++)
      #pragma unroll
      for (int j = 0; j < NJ; j++)
        acc[i][j] = __builtin_amdgcn_mfma_f32_16x16x32_bf16(af[i], bfr[j], acc[i][j], 0, 0, 0);
  }

  long zc = (long)bo * cOuter + (long)bi_ * cInner;
  #pragma unroll
  for (int i = 0; i < 4; i++){
    #pragma unroll
    for (int j = 0; j < NJ; j++){
      #pragma unroll
      for (int r = 0; r < 4; r++){
        int m = m0 + wm + i * 16 + kg * 4 + r;
        int n = n0 + wn + j * 16 + lr;
        float v = acc[i][j][r];
        if constexpr (MODE == 4){
          float gate = fsigmoid(v + bias[n]);
          int bt = m >> 12;
          float yr = bf2f(gy[(long)m * ldc + ginv[bt * CH + n]]);
          Ch[(long)m * ldc + n] = f2bf(yr * gate);
        }
      }
    }
  }
}

// ---------------- fused dt GEMM + chunk-scan (p1), both directions per block ----------------
// grid (3, 64, 16): z = bg. Shares the A tile and xv reads between k=0 and k=1.
// Dual scan buffers: both directions scanned concurrently by half-blocks.
__global__ __launch_bounds__(256) void k_dt(
    const u16* __restrict__ xcvh, const u16* __restrict__ Mw,
    const float* __restrict__ dtb, const float* __restrict__ Atab,
    const float* __restrict__ bc, u16* __restrict__ pk16,
    float* __restrict__ cP, float* __restrict__ cS){
  __shared__ unsigned sMem[2 * 64 * 64];   // 32 KB: staging (12 KB) then 2 scan buffers
  u16* sA  = (u16*)sMem;                   // [0, 4 KB)
  u16* sB0 = (u16*)(sMem + 1024);          // [4, 8 KB)
  u16* sB1 = (u16*)(sMem + 2048);          // [8, 12 KB)

  int bg = blockIdx.z;
  int g = bg & 1;
  int gk0 = g * 2, gk1 = g * 2 + 1;
  const u16* Ab  = xcvh + (long)bg * LTOK * 192;
  const u16* Bb0 = Mw + (long)gk0 * 36864;
  const u16* Bb1 = Mw + (long)gk1 * 36864;
  int tid = threadIdx.x;
  int m0 = blockIdx.y * 64, n0 = blockIdx.x * 64;
  int wv = tid >> 6, l = tid & 63;
  int wm = (wv >> 1) * 32, wn = (wv & 1) * 32;
  int kg = l >> 4, lr = l & 15;

  f32x4 acc0[2][2], acc1[2][2];
  #pragma unroll
  for (int i = 0; i < 2; i++)
    #pragma unroll
    for (int j = 0; j < 2; j++)
      #pragma unroll
      for (int r = 0; r < 4; r++){ acc0[i][j][r] = 0.f; acc1[i][j][r] = 0.f; }

  int aoffU[2], boffU[2];
  #pragma unroll
  for (int i = 0; i < 2; i++){
    int r = wm + i * 16 + lr;
    aoffU[i] = r * 32 + ((kg * 8) ^ ((r & 3) << 3));
  }
  #pragma unroll
  for (int j = 0; j < 2; j++){
    int r = wn + j * 16 + lr;
    boffU[j] = r * 32 + ((kg * 8) ^ ((r & 3) << 3));
  }

  int srow = tid >> 2, sss = (tid & 3) ^ (srow & 3);
  int wb = tid & 192;
  const int nks = 6;   // K = 192
  for (int ks = 0; ks < nks; ks++){
    int k0 = ks << 5;
    __syncthreads();
    gl16(Ab  + (long)(m0 + srow) * 192 + k0 + sss * 8, sA  + wb * 8);
    gl16(Bb0 + (long)(n0 + srow) * 192 + k0 + sss * 8, sB0 + wb * 8);
    gl16(Bb1 + (long)(n0 + srow) * 192 + k0 + sss * 8, sB1 + wb * 8);
    __syncthreads();
    s16x8 af[2], b0[2], b1[2];
    #pragma unroll
    for (int i = 0; i < 2; i++) af[i] = *(const s16x8*)(sA + aoffU[i]);
    #pragma unroll
    for (int j = 0; j < 2; j++){ b0[j] = *(const s16x8*)(sB0 + boffU[j]);
                                 b1[j] = *(const s16x8*)(sB1 + boffU[j]); }
    #pragma unroll
    for (int i = 0; i < 2; i++)
      #pragma unroll
      for (int j = 0; j < 2; j++){
        acc0[i][j] = __builtin_amdgcn_mfma_f32_16x16x32_bf16(af[i], b0[j], acc0[i][j], 0, 0, 0);
        acc1[i][j] = __builtin_amdgcn_mfma_f32_16x16x32_bf16(af[i], b1[j], acc1[i][j], 0, 0, 0);
      }
  }

  // epilogue: both directions; one scattered xv read shared
  unsigned pk0[2][2][4], pk1[2][2][4];
  float dtb0[2], Atl0[2], dtb1[2], Atl1[2];
  #pragma unroll
  for (int j = 0; j < 2; j++){
    int n = n0 + wn + j * 16 + lr;
    dtb0[j] = dtb[gk0 * 192 + n];  Atl0[j] = Atab[gk0 * 192 + n];
    dtb1[j] = dtb[gk1 * 192 + n];  Atl1[j] = Atab[gk1 * 192 + n];
  }
  #pragma unroll
  for (int i = 0; i < 2; i++){
    #pragma unroll
    for (int r = 0; r < 4; r++){
      int ml = wm + i * 16 + kg * 4 + r;
      int m = m0 + ml;
      long rowz0 = ((long)bg * 2) * LTOK + m;
      long rowz1 = rowz0 + LTOK;
      long rowx  = (long)bg * LTOK + m;
      float Bv0 = bc[rowz0 * 2], Bv1 = bc[rowz1 * 2];
      float d0s[2], d1s[2];
      #pragma unroll
      for (int j = 0; j < 2; j++){
        int n = n0 + wn + j * 16 + lr;
        float xv = bf2f(xcvh[rowx * 192 + n]);
        float r0 = acc0[i][j][r] + dtb0[j];
        float t0 = __logf(1.f + __expf(r0));
        float a0 = __expf(Atl0[j] * t0);
        float r1 = acc1[i][j][r] + dtb1[j];
        float t1 = __logf(1.f + __expf(r1));
        float a1 = __expf(Atl1[j] * t1);
        d0s[j] = t0; d1s[j] = t1;
        pk0[i][j][r] = cvt_pk_bf16(a0, t0 * Bv0 * xv);
        pk1[i][j][r] = cvt_pk_bf16(a1, t1 * Bv1 * xv);
      }
      unsigned p0 = cvt_pk_bf16(d0s[0], d0s[1]);
      pk16[rowz0 * 192 + n0 + wn + lr]      = (u16)(p0 & 0xFFFFu);
      pk16[rowz0 * 192 + n0 + wn + 16 + lr] = (u16)(p0 >> 16);
      unsigned p1 = cvt_pk_bf16(d1s[0], d1s[1]);
      pk16[rowz1 * 192 + n0 + wn + lr]      = (u16)(p1 & 0xFFFFu);
      pk16[rowz1 * 192 + n0 + wn + 16 + lr] = (u16)(p1 >> 16);
    }
  }

  // write both packed buffers, one barrier, dual-parallel scan
  __syncthreads();
  #pragma unroll
  for (int i = 0; i < 2; i++)
    #pragma unroll
    for (int j = 0; j < 2; j++)
      #pragma unroll
      for (int r = 0; r < 4; r++){
        int ml = wm + i * 16 + kg * 4 + r;
        int cl = wn + j * 16 + lr;
        sMem[ml * 64 + SCOL(ml, cl)]        = pk0[i][j][r];
        sMem[4096 + ml * 64 + SCOL(ml, cl)] = pk1[i][j][r];
      }
  __syncthreads();
  {
    int dir = tid >> 7;            // 0: forward (k=0), 1: reverse (k=1)
    int t2 = tid & 127;
    int cc = t2 >> 6, nn = t2 & 63;
    const unsigned* buf = sMem + dir * 4096;
    float P = 1.f, S = 0.f;
    if (dir == 0){
      for (int s = 0; s < CHS; s++){
        int row = cc * CHS + s;
        unsigned v = buf[row * 64 + SCOL(row, nn)];
        float a = bf2f((u16)(v & 0xFFFFu));
        float dBx = bf2f((u16)(v >> 16));
        P *= a; S = a * S + dBx;
      }
    } else {
      for (int s = CHS - 1; s >= 0; s--){
        int row = cc * CHS + s;
        unsigned v = buf[row * 64 + SCOL(row, nn)];
        float a = bf2f((u16)(v & 0xFFFFu));
        float dBx = bf2f((u16)(v >> 16));
        P *= a; S = a * S + dBx;
      }
    }
    int cglob = (dir == 0) ? (blockIdx.y * 2 + cc)
                           : (NCHK - 1 - blockIdx.y * 2 - cc);
    long idx = (((long)bg * 2 + dir) * NCHK + cglob) * 192 + n0 + nn;
    cP[idx] = P;
    cS[idx] = S;
  }
}

// ---------------- depthwise 3x3 conv (u16x8/thread) + fused B/C projection ----------------
__global__ __launch_bounds__(192) void k_conv(const u16* __restrict__ xch,
    const u16* __restrict__ cwb, const float* __restrict__ cb,
    const float* __restrict__ xpw, u16* __restrict__ xcvh,
    float* __restrict__ bc){
  __shared__ float red[8][4][25];
  int tid = threadIdx.x;
  int chg = tid % 24, pp = tid / 24;    // 24 channel-groups x 8 positions
  int p = blockIdx.x * 8 + pp;
  int bg = blockIdx.y; int g = bg & 1;
  int h = p >> 6, w = p & 63;
  int di = chg * 8;
  long sb = (long)bg * LTOK;

  u16x8 wv[9];
  #pragma unroll
  for (int t = 0; t < 9; t++)
    wv[t] = *(const u16x8*)(cwb + ((long)g * 9 + t) * DH + di);

  float acc[8];
  #pragma unroll
  for (int j = 0; j < 8; j++) acc[j] = cb[g * DH + di + j];

  #pragma unroll
  for (int dh = -1; dh <= 1; dh++){
    int hh = h + dh; if (hh < 0 || hh >= HH) continue;
    #pragma unroll
    for (int dw = -1; dw <= 1; dw++){
      int ww2 = w + dw; if (ww2 < 0 || ww2 >= WW) continue;
      u16x8 xv = *(const u16x8*)(xch + (sb + hh * WW + ww2) * DH + di);
      int t = (dh + 1) * 3 + (dw + 1);
      #pragma unroll
      for (int j = 0; j < 8; j++) acc[j] += bf2f(wv[t][j]) * bf2f(xv[j]);
    }
  }

  u16x8 ov;
  #pragma unroll
  for (int j = 0; j < 8; j++){
    float s = acc[j];
    acc[j] = s * fsigmoid(s);         // post-silu fp32, reused for B/C dot
    ov[j] = f2bf(acc[j]);
  }
  int lscan = (g == 0) ? p : (w * HH + h);
  *(u16x8*)(xcvh + (sb + lscan) * DH + di) = ov;

  // B/C projection partials
  #pragma unroll
  for (int j = 0; j < 4; j++){
    int k = j >> 1, ci = j & 1;
    const float* wl = xpw + (long)g * 5376 + (k * 14 + 12 + ci) * 192 + di;
    float sacc = 0.f;
    #pragma unroll
    for (int q = 0; q < 8; q++) sacc += acc[q] * wl[q];
    red[pp][j][chg] = sacc;
  }
  __syncthreads();
  if (tid < 32){
    int pos = tid >> 2, j = tid & 3;
    float ssum = 0.f;
    #pragma unroll
    for (int q = 0; q < 24; q++) ssum += red[pos][j][q];
    int p2 = blockIdx.x * 8 + pos;
    int h2 = p2 >> 6, w2 = p2 & 63;
    int ls = (g == 0) ? p2 : (w2 * HH + h2);
    int k = j >> 1;
    bc[(((long)(bg * 2 + k)) * LTOK + ls) * 2 + (j & 1)] = ssum;
  }
}

// ---------------- scan p2: sequential composition over 128 chunks ----------------
__global__ __launch_bounds__(192) void k_scan_p2(const float* __restrict__ cP,
    const float* __restrict__ cS, float* __restrict__ h0){
  int z = blockIdx.x;              // 0..31
  int di = threadIdx.x;
  float h = 0.f;
  for (int c = 0; c < NCHK; c++){
    long idx = ((long)z * NCHK + c) * 192 + di;
    h0[idx] = h;
    h = cP[idx] * h + cS[idx];
  }
}

// ---------------- scan p3 fused: both directions in regs + out-LN + *siluz -> yab ----------------
__global__ __launch_bounds__(192) void k_scan_p3(const u16* __restrict__ pk16,
    const u16* __restrict__ xcvh, const float* __restrict__ bc,
    const float* __restrict__ Atab, const float* __restrict__ ds,
    const float* __restrict__ h0, const u16* __restrict__ zsh,
    const float* __restrict__ ong, const float* __restrict__ onb,
    u16* __restrict__ yab){
  __shared__ float yl[CHS][193];
  __shared__ float red[2][32][6];
  __shared__ float minv[2][32];
  int bg = blockIdx.x, c = blockIdx.y;
  int g = bg & 1;
  int di = threadIdx.x;
  const u16* xc = xcvh + (long)bg * LTOK * 192 + di;
  int l0 = c * CHS;
  float yv[CHS];

  // forward direction (k=0)
  {
    int z = bg * 2, gk = g * 2;
    float Dv = ds[gk * 192 + di], Av = Atab[gk * 192 + di];
    const u16* pk = pk16 + (long)z * LTOK * 192 + di;
    const float* bcp = bc + (long)z * LTOK * 2;
    float h = h0[((long)z * NCHK + c) * 192 + di];
    #pragma unroll
    for (int s = 0; s < CHS; s++){
      int l = l0 + s;
      float dtv = bf2f(pk[(long)l * 192]);
      float av  = __expf(Av * dtv);
      float xv  = bf2f(xc[(long)l * 192]);
      float Bv  = bcp[l * 2], Cv = bcp[l * 2 + 1];
      h = av * h + dtv * Bv * xv;
      yv[s] = h * Cv + Dv * xv;
    }
  }
  // backward direction (k=1) covers the same positions
  {
    int z = bg * 2 + 1, gk = g * 2 + 1;
    float Dv = ds[gk * 192 + di], Av = Atab[gk * 192 + di];
    const u16* pk = pk16 + (long)z * LTOK * 192 + di;
    const float* bcp = bc + (long)z * LTOK * 2;
    int cc = NCHK - 1 - c;
    float h = h0[((long)z * NCHK + cc) * 192 + di];
    #pragma unroll
    for (int s = CHS - 1; s >= 0; s--){
      int l = l0 + s;
      float dtv = bf2f(pk[(long)l * 192]);
      float av  = __expf(Av * dtv);
      float xv  = bf2f(xc[(long)l * 192]);
      float Bv  = bcp[l * 2], Cv = bcp[l * 2 + 1];
      h = av * h + dtv * Bv * xv;
      yv[s] += h * Cv + Dv * xv;
    }
  }

  // out-LN across channels per position (192 threads = all channels)
  #pragma unroll
  for (int s = 0; s < CHS; s++) yl[s][di] = yv[s];
  __syncthreads();
  {
    int pos = di & 31, seg = di >> 5;
    float s1 = 0.f, s2 = 0.f;
    #pragma unroll
    for (int q = 0; q < 32; q++){
      float v = yl[pos][seg * 32 + q];
      s1 += v; s2 += v * v;
    }
    red[0][pos][seg] = s1;
    red[1][pos][seg] = s2;
  }
  __syncthreads();
  if (di < 32){
    float s1 = 0.f, s2 = 0.f;
    #pragma unroll
    for (int q = 0; q < 6; q++){ s1 += red[0][di][q]; s2 += red[1][di][q]; }
    float m = s1 * (1.f / DH);
    float var = s2 * (1.f / DH) - m * m;
    minv[0][di] = m;
    minv[1][di] = rsqrtf(var + 1e-5f);
  }
  __syncthreads();

  float gng = ong[g * 192 + di], gnb = onb[g * 192 + di];
  long zbase = (long)bg * LTOK;
  #pragma unroll
  for (int s = 0; s < CHS; s++){
    int l = l0 + s;
    int p = (g == 0) ? l : ((l & 63) * 64 + (l >> 6));
    float m = minv[0][s], inv = minv[1][s];
    float yln = (yv[s] - m) * inv * gng + gnb;
    float zs = bf2f(zsh[(zbase + p) * 192 + di]);   // pre-silu'd z
    yab[(zbase + p) * 192 + di] = f2bf(yln * zs);
  }
}

extern "C" void kernel_launch(void* const* d_in, const int* in_sizes, int n_in,
                              void* d_out, int out_size, void* d_ws, size_t ws_size,
                              hipStream_t stream){
  const float* x       = (const float*)d_in[0];
  const float* norm_g  = (const float*)d_in[1];
  const float* norm_b  = (const float*)d_in[2];
  const float* r_w1    = (const float*)d_in[3];
  const float* r_b1    = (const float*)d_in[4];
  const float* r_w2    = (const float*)d_in[5];
  const float* r_b2    = (const float*)d_in[6];
  const float* in_proj = (const float*)d_in[7];
  const float* conv_w  = (const float*)d_in[8];
  const float* conv_b  = (const float*)d_in[9];
  const float* xp_w    = (const float*)d_in[10];
  const float* dt_w    = (const float*)d_in[11];
  const float* dt_b    = (const float*)d_in[12];
  const float* A_log   = (const float*)d_in[13];
  const float* Ds      = (const float*)d_in[14];
  const float* on_g    = (const float*)d_in[15];
  const float* on_b    = (const float*)d_in[16];
  const float* op_w    = (const float*)d_in[17];
  const float* ci_w1   = (const float*)d_in[18];
  const float* ci_b1   = (const float*)d_in[19];
  const float* ci_w2   = (const float*)d_in[20];
  const float* ci_b2   = (const float*)d_in[21];
  const float* proj_w  = (const float*)d_in[22];
  const float* proj_b  = (const float*)d_in[23];
  const float* skip    = (const float*)d_in[24];
  float* out = (float*)d_out;
  float* ws  = (float*)d_ws;

  // Regions (floats):
  // R1 = ws[0 .. BLC)         : xn fp32 -> pk16 u16
  // R2 = [BLC .. 2*BLC)       : xcbh bf16 -> gab bf16
  // R3 = [2*BLC .. 2.5*BLC)   : zsh bf16 -> ycat bf16
  // R4 = [2.5B .. 3*BLC)      : xcvh bf16
  // R5 = [3*BLC .. 3.5*BLC)   : As bf16 -> yab bf16
  float* xn   = ws;
  float* xcb  = ws + BLC;
  float* R3   = ws + 2 * BLC;
  float* R4   = R3 + BLC / 2;
  float* R5   = R4 + BLC / 2;
  float* pp   = R5 + BLC / 2;
  int*  sidx  = (int*)(pp + NB * 16 * CH);
  int*  inv   = sidx + NB * CH;
  u16*  wip   = (u16*)(inv + NB * CH);   // 2*384*192
  u16*  wop   = wip + 2 * 384 * 192;     // 2*192*192
  u16*  wpj   = wop + 2 * 192 * 192;     // 384*384
  u16*  w1g   = wpj + 384 * 384;         // NB*32*384
  u16*  w2p   = w1g + NB * 32 * CH;      // 384*32
  u16*  Mw    = w2p + CH * 32;           // 4*192*192
  u16*  cwb   = Mw + 4 * 192 * 192;      // 2*9*192
  float* b1p  = (float*)(cwb + 2 * 9 * DH);
  float* Atab = b1p + 32;                // 4*192
  u16*  hidp  = (u16*)(Atab + 4 * 192);  // NB*4096*32
  float* bc   = (float*)(hidp + (long)NB * LTOK * 32);  // 32*4096*2
  float* cP   = bc + 32 * LTOK * 2;
  float* cS   = cP + CST;
  float* h0   = cS + CST;

  size_t need = ((size_t)(2 * BLC) + 3 * (BLC / 2) + NB * 16 * CH + 32 * LTOK * 2 + 3 * CST + 64) * 4
              + (size_t)(2 * NB * CH) * 4 + (size_t)(4 * 192 + 32) * 4
              + ((size_t)2*384*192 + 2*192*192 + 384*384 + NB*32*CH + CH*32 + 4*192*192
                 + 2*9*DH + (size_t)NB * LTOK * 32) * 2
              + 8192;
  if (ws_size < need) return;

  // aliases
  u16*  As   = (u16*)R5;
  u16*  zsh  = (u16*)R3;                // silu(z) bf16
  u16*  xcbh = (u16*)xcb;               // bf16 conv input (R2)
  u16*  xcvh = (u16*)R4;
  u16*  pk16 = (u16*)ws;                // bf16 dt stash in R1 (xn dead after castgather)
  u16*  yab  = (u16*)R5;                // As dead after k_hid
  u16*  ycat = (u16*)R3;                // zsh dead after fused p3
  u16*  gab  = (u16*)xcb;               // R2, xcbh dead after conv

  k_ln<<<NB * LTOK, 128, 0, stream>>>(x, norm_g, norm_b, xn);
  k_preps<<<2033, 256, 0, stream>>>(in_proj, op_w, proj_w, A_log, conv_w,
                                    dt_w, xp_w, wip, wop, wpj, Atab, cwb, Mw);
  k_pool<<<dim3(3, 16, NB), 128, 0, stream>>>(xn, pp);
  k_score<<<NB, 384, 0, stream>>>(pp, r_w1, r_b1, r_w2, r_b2, sidx, inv);
  k_castgather<<<NB * LTOK, 384, 0, stream>>>(xn, sidx, As);
  k_prepw<<<NB + 1, 256, 0, stream>>>(ci_w1, ci_b1, ci_w2, sidx, w1g, w2p, b1p);

  // in_proj: per (b,g): [4096x192]@[384x192]^T -> xcbh bf16 + zsh=silu(z) bf16
  k_mm2<1, 1><<<dim3(6, 64, 16), 256, 0, stream>>>(
      As, CH, (long)LTOK * CH, 192,
      wip, 192, (long)384 * 192,
      (float*)xcbh, zsh, (long)2 * LTOK * DH, (long)LTOK * DH, 0,
      2, nullptr, nullptr, nullptr);

  // gate stage 1 (uses As; before R5 is recycled as yab)
  k_hid<<<dim3(32, NB), 256, 0, stream>>>(As, w1g, b1p, hidp);

  // conv + fused B/C projection
  k_conv<<<dim3(LTOK / 8, NB * 2), 192, 0, stream>>>(xcbh, cwb, conv_b, xp_w, xcvh, bc);

  // fused dt GEMM + chunk scan (p1), both directions per block -> pk16 + cP/cS
  k_dt<<<dim3(3, 64, 16), 256, 0, stream>>>(xcvh, Mw, dt_b, Atab, bc, pk16, cP, cS);

  k_scan_p2<<<32, 192, 0, stream>>>(cP, cS, h0);

  // fused p3: both directions + out-LN + *silu(z) -> yab
  k_scan_p3<<<dim3(NB * 2, NCHK), 192, 0, stream>>>(
      pk16, xcvh, bc, Atab, Ds, h0, zsh, on_g, on_b, yab);

  // out_proj: per (b,g): [4096x192]@[192x192]^T -> ycat bf16 (col offset g*192)
  k_mm2<1, 2><<<dim3(3, 64, 16), 256, 0, stream>>>(
      yab, DH, (long)2 * LTOK * DH, (long)LTOK * DH,
      wop, 192, (long)192 * 192,
      nullptr, ycat, (long)LTOK * CH, 192, CH,
      2, nullptr, nullptr, nullptr);

  // gate stage 2 + un-sort gather + multiply
  k_mm<128, 4><<<dim3(3, 256, 1), 256, 0, stream>>>(
      hidp, 32, 0, 0,
      w2p, 0,
      nullptr, gab, 0, 0, CH,
      32, 1, ci_b2, nullptr, nullptr, ycat, inv);

  // final: out = x + skip * (gab @ proj_w^T + proj_b)
  k_mm2<2, 3><<<dim3(6, 512, 1), 256, 0, stream>>>(
      gab, CH, 0, 0,
      wpj, 384, 0,
      out, nullptr, 0, 0, CH,
      1, proj_b, x, skip);
}